// Round 1
// baseline (2395.518 us; speedup 1.0000x reference)
//
#include <hip/hip_runtime.h>

// Problem constants (from reference): T=512, N=512, I=256, H=256
#define kT 512
#define kN 512
#define kH 256
#define kG3 768   // 3*H

typedef float  f32x4  __attribute__((ext_vector_type(4)));
typedef __bf16 bf16x8 __attribute__((ext_vector_type(8)));
typedef __bf16 bf16x4 __attribute__((ext_vector_type(4)));

static __device__ __forceinline__ float sigm(float x) {
  float e = __builtin_amdgcn_exp2f(-1.4426950408889634f * x);
  return __builtin_amdgcn_rcpf(1.0f + e);
}
static __device__ __forceinline__ float tanh_fast(float x) {
  float e = __builtin_amdgcn_exp2f(-2.8853900817779268f * x);
  return fmaf(2.0f, __builtin_amdgcn_rcpf(1.0f + e), -1.0f);
}

// ---------------------------------------------------------------------------
// Phase 1: gi = x @ W_ih^T + b_ih (+ b_hh for r,z gates), bf16, swizzled layout.
// Layout: gi_swz[t][seqblk(32)][w2(8)][gate(3)][lane(64)][8 bf16]
//   lane l, elem e: value for seq row s=(l>>4)*4+(e&3), col j=gate*256+w2*32+(e>>2)*16+(l&15)
// Grid: (6 N-blocks, 2048 M-blocks), block 256 thr (4 waves, 2x2).
// ---------------------------------------------------------------------------
__global__ __launch_bounds__(256) void gi_gemm(
    const float* __restrict__ x, const float* __restrict__ Wih,
    const float* __restrict__ bih, const float* __restrict__ bhh,
    __bf16* __restrict__ gis)
{
  __shared__ __align__(16) __bf16 Al[128][72];  // 64 k + 8 pad
  __shared__ __align__(16) __bf16 Bl[128][72];
  const int tid  = threadIdx.x;
  const int lane = tid & 63, w = tid >> 6;
  const int wm = w & 1, wn = w >> 1;
  const int  Nblk = blockIdx.x;            // 0..5
  const long Mblk = blockIdx.y;            // 0..2047
  const long R0 = Mblk * 128;
  const int  jb = Nblk * 128;
  const int  gate = jb >> 8;
  const int  t  = (int)(R0 >> 9);
  const int  n0 = (int)(R0 & 511);

  f32x4 acc[4][4];
  #pragma unroll
  for (int nt = 0; nt < 4; ++nt) {
    int j = jb + wn * 64 + nt * 16 + (lane & 15);
    float bv = bih[j] + (gate < 2 ? bhh[j] : 0.0f);
    #pragma unroll
    for (int mt = 0; mt < 4; ++mt) acc[mt][nt] = (f32x4){bv, bv, bv, bv};
  }

  for (int kb = 0; kb < 256; kb += 64) {
    __syncthreads();
    #pragma unroll
    for (int g = 0; g < 8; ++g) {
      int slot = tid + g * 256;            // 0..2047
      int r  = slot >> 4;                  // 0..127
      int kq = (slot & 15) * 4;            // 0..60
      float4 av = *(const float4*)(x   + (R0 + r) * 256 + kb + kq);
      float4 bv = *(const float4*)(Wih + (long)(jb + r) * 256 + kb + kq);
      bf16x4 a4 = {(__bf16)av.x, (__bf16)av.y, (__bf16)av.z, (__bf16)av.w};
      bf16x4 b4 = {(__bf16)bv.x, (__bf16)bv.y, (__bf16)bv.z, (__bf16)bv.w};
      *(bf16x4*)(&Al[r][kq]) = a4;
      *(bf16x4*)(&Bl[r][kq]) = b4;
    }
    __syncthreads();
    #pragma unroll
    for (int ss = 0; ss < 2; ++ss) {
      bf16x8 af[4], bf[4];
      #pragma unroll
      for (int mt = 0; mt < 4; ++mt)
        af[mt] = *(const bf16x8*)(&Al[wm * 64 + mt * 16 + (lane & 15)][ss * 32 + (lane >> 4) * 8]);
      #pragma unroll
      for (int nt = 0; nt < 4; ++nt)
        bf[nt] = *(const bf16x8*)(&Bl[wn * 64 + nt * 16 + (lane & 15)][ss * 32 + (lane >> 4) * 8]);
      #pragma unroll
      for (int mt = 0; mt < 4; ++mt)
        #pragma unroll
        for (int nt = 0; nt < 4; ++nt)
          acc[mt][nt] = __builtin_amdgcn_mfma_f32_16x16x32_bf16(af[mt], bf[nt], acc[mt][nt], 0, 0, 0);
    }
  }

  // Epilogue: swizzled coalesced stores (one dwordx4 per (pair, mt) per lane)
  #pragma unroll
  for (int p = 0; p < 2; ++p) {
    int j8 = jb + wn * 64 + p * 32;
    int w2 = (j8 & 255) >> 5;
    #pragma unroll
    for (int mt = 0; mt < 4; ++mt) {
      int sb = (n0 >> 4) + wm * 4 + mt;
      bf16x8 v;
      #pragma unroll
      for (int i = 0; i < 4; ++i) {
        v[i]     = (__bf16)acc[mt][2 * p][i];
        v[4 + i] = (__bf16)acc[mt][2 * p + 1][i];
      }
      long base = ((((long)t * 32 + sb) * 8 + w2) * 3 + gate) * 512 + lane * 8;
      *(bf16x8*)(gis + base) = v;
    }
  }
}

// ---------------------------------------------------------------------------
// Phase 2: recurrent scan. 32 blocks x 512 thr (8 waves). Block b owns seqs
// [16b,16b+16). W_hh held entirely in VGPRs (48 bf16x8 frags/wave = 192 VGPR).
// h broadcast via 16KB XOR-swizzled double-buffered LDS. One barrier/step.
// ---------------------------------------------------------------------------
__global__ __launch_bounds__(512, 2) void gru_scan(
    const __bf16* __restrict__ gis, const float* __restrict__ h0,
    const float* __restrict__ done, const float* __restrict__ Whh,
    const float* __restrict__ bhh, float* __restrict__ out)
{
  __shared__ __align__(16) __bf16 hbuf[2][16 * 256];
  const int tid  = threadIdx.x;
  const int lane = tid & 63, w2 = tid >> 6;
  const int b  = blockIdx.x;
  const int nb = b * 16;
  const int c  = lane & 15, lg = lane >> 4;

  // --- W_hh fragments -> registers (bf16). tt = gate*2 + tprime.
  bf16x8 wf[48];
  #pragma unroll
  for (int tt = 0; tt < 6; ++tt) {
    const int g = tt >> 1, tp = tt & 1;
    const int j = g * 256 + w2 * 32 + tp * 16 + c;
    #pragma unroll
    for (int ss = 0; ss < 8; ++ss) {
      const int k0 = ss * 32 + lg * 8;
      float4 q0 = *(const float4*)(Whh + (long)j * 256 + k0);
      float4 q1 = *(const float4*)(Whh + (long)j * 256 + k0 + 4);
      bf16x8 v = {(__bf16)q0.x, (__bf16)q0.y, (__bf16)q0.z, (__bf16)q0.w,
                  (__bf16)q1.x, (__bf16)q1.y, (__bf16)q1.z, (__bf16)q1.w};
      wf[tt * 8 + ss] = v;
    }
  }
  const float bn0 = bhh[512 + w2 * 32 + c];
  const float bn1 = bhh[512 + w2 * 32 + 16 + c];

  // --- init h (scaled by 1-done[0]) into LDS buf0 + per-lane h_old
  {
    const int s  = tid >> 5;
    const int kk = (tid & 31) * 8;
    float sc = 1.0f - done[nb + s];
    const float* hp = h0 + (long)(nb + s) * 256 + kk;
    bf16x8 v;
    #pragma unroll
    for (int e = 0; e < 8; ++e) v[e] = (__bf16)(hp[e] * sc);
    int colb = (kk * 2) ^ ((s & 7) << 4);
    *(bf16x8*)(&hbuf[0][s * 256 + (colb >> 1)]) = v;
  }
  float hold[4][2];
  #pragma unroll
  for (int i = 0; i < 4; ++i) {
    int s = lg * 4 + i;
    float sc = 1.0f - done[nb + s];
    #pragma unroll
    for (int tp = 0; tp < 2; ++tp)
      hold[i][tp] = h0[(long)(nb + s) * 256 + w2 * 32 + tp * 16 + c] * sc;
  }
  __syncthreads();

  // --- prefetch gi(t=0)
  bf16x8 gfr[3];
  {
    long gb = (((long)0 * 32 + b) * 8 + w2) * 3 * 512 + lane * 8;
    #pragma unroll
    for (int g = 0; g < 3; ++g) gfr[g] = *(const bf16x8*)(gis + gb + g * 512);
  }

  float* outF = out + (long)kT * kN * kH;
  int p = 0;
  #pragma unroll 1
  for (int t = 0; t < kT; ++t) {
    // acc init: r,z tiles from gi (biases folded in phase1); n tiles = b_hh_n
    f32x4 acc[6];
    #pragma unroll
    for (int g = 0; g < 2; ++g)
      #pragma unroll
      for (int tp = 0; tp < 2; ++tp) {
        f32x4 a;
        #pragma unroll
        for (int i = 0; i < 4; ++i) a[i] = (float)gfr[g][tp * 4 + i];
        acc[g * 2 + tp] = a;
      }
    acc[4] = (f32x4){bn0, bn0, bn0, bn0};
    acc[5] = (f32x4){bn1, bn1, bn1, bn1};

    // MFMA over K=256 (8 slices); A from swizzled LDS, B from registers
    const __bf16* hb = hbuf[p];
    const int rx = (c & 7) << 4;
    #pragma unroll
    for (int ss = 0; ss < 8; ++ss) {
      int colb = (ss * 64 + lg * 16) ^ rx;
      bf16x8 afr = *(const bf16x8*)(&hb[c * 256 + (colb >> 1)]);
      #pragma unroll
      for (int tt = 0; tt < 6; ++tt)
        acc[tt] = __builtin_amdgcn_mfma_f32_16x16x32_bf16(afr, wf[tt * 8 + ss], acc[tt], 0, 0, 0);
    }

    // done(t+1) (hidden under gates)
    float dn[4];
    #pragma unroll
    for (int i = 0; i < 4; ++i)
      dn[i] = (t < kT - 1) ? done[(long)(t + 1) * kN + nb + lg * 4 + i] : 0.0f;

    // gates + state update + stores
    float* op = out + ((long)t * kN + nb) * kH;
    __bf16* hw = hbuf[p ^ 1];
    #pragma unroll
    for (int i = 0; i < 4; ++i) {
      const int s = lg * 4 + i;
      #pragma unroll
      for (int tp = 0; tp < 2; ++tp) {
        float r  = sigm(acc[tp][i]);
        float z  = sigm(acc[2 + tp][i]);
        float np = (float)gfr[2][tp * 4 + i] + r * acc[4 + tp][i];
        float n  = tanh_fast(np);
        float ho = hold[i][tp];
        float hn = n + z * (ho - n);
        const int jh = w2 * 32 + tp * 16 + c;
        op[(long)s * kH + jh] = hn;
        if (t == kT - 1) outF[(long)(nb + s) * kH + jh] = hn;
        float hk = hn * (1.0f - dn[i]);
        hold[i][tp] = hk;
        int colb = (jh * 2) ^ ((s & 7) << 4);
        hw[s * 256 + (colb >> 1)] = (__bf16)hk;
      }
    }

    // prefetch gi(t+1) so next step's acc-init doesn't stall on HBM
    {
      int tn = (t < kT - 1) ? t + 1 : t;
      long gb = (((long)tn * 32 + b) * 8 + w2) * 3 * 512 + lane * 8;
      #pragma unroll
      for (int g = 0; g < 3; ++g) gfr[g] = *(const bf16x8*)(gis + gb + g * 512);
    }
    __syncthreads();
    p ^= 1;
  }
}

// ---------------------------------------------------------------------------
// Fallback (only if ws too small for gi): naive fp32, correct but slow.
// ---------------------------------------------------------------------------
__global__ __launch_bounds__(256) void gru_naive(
    const float* __restrict__ x, const float* __restrict__ h0,
    const float* __restrict__ done, const float* __restrict__ Wih,
    const float* __restrict__ Whh, const float* __restrict__ bih,
    const float* __restrict__ bhh, float* __restrict__ out)
{
  __shared__ float hsA[16][257];
  __shared__ float hsB[16][257];
  const int tid = threadIdx.x;       // column jh
  const int b = blockIdx.x, nb = b * 16;
  for (int s = 0; s < 16; ++s)
    hsA[s][tid] = h0[(long)(nb + s) * 256 + tid] * (1.0f - done[nb + s]);
  __syncthreads();
  float (*hr)[257] = hsA;
  float (*hw)[257] = hsB;
  float* outF = out + (long)kT * kN * kH;
  for (int t = 0; t < kT; ++t) {
    for (int s = 0; s < 16; ++s) {
      const float* xr = x + ((long)t * kN + nb + s) * 256;
      float pr  = bih[tid] + bhh[tid];
      float pz  = bih[256 + tid] + bhh[256 + tid];
      float pnx = bih[512 + tid];
      float pnh = bhh[512 + tid];
      const float* wr = Wih + (long)tid * 256;
      const float* wz = Wih + (long)(256 + tid) * 256;
      const float* wn = Wih + (long)(512 + tid) * 256;
      const float* vr = Whh + (long)tid * 256;
      const float* vz = Whh + (long)(256 + tid) * 256;
      const float* vn = Whh + (long)(512 + tid) * 256;
      #pragma unroll 4
      for (int k = 0; k < 256; ++k) {
        float xv = xr[k], hv = hr[s][k];
        pr  = fmaf(xv, wr[k], pr);  pr  = fmaf(hv, vr[k], pr);
        pz  = fmaf(xv, wz[k], pz);  pz  = fmaf(hv, vz[k], pz);
        pnx = fmaf(xv, wn[k], pnx); pnh = fmaf(hv, vn[k], pnh);
      }
      float r = sigm(pr), z = sigm(pz);
      float n = tanh_fast(pnx + r * pnh);
      float ho = hr[s][tid];
      float hn = n + z * (ho - n);
      out[((long)t * kN + nb + s) * 256 + tid] = hn;
      if (t == kT - 1) outF[(long)(nb + s) * 256 + tid] = hn;
      float d = (t < kT - 1) ? done[(long)(t + 1) * kN + nb + s] : 0.0f;
      hw[s][tid] = hn * (1.0f - d);
    }
    __syncthreads();
    float (*tmp)[257] = hr; hr = hw; hw = tmp;
  }
}

extern "C" void kernel_launch(void* const* d_in, const int* in_sizes, int n_in,
                              void* d_out, int out_size, void* d_ws, size_t ws_size,
                              hipStream_t stream) {
  const float* x    = (const float*)d_in[0];
  const float* h0   = (const float*)d_in[1];
  const float* done = (const float*)d_in[2];
  const float* Wih  = (const float*)d_in[3];
  const float* Whh  = (const float*)d_in[4];
  const float* bih  = (const float*)d_in[5];
  const float* bhh  = (const float*)d_in[6];
  float* out = (float*)d_out;

  const size_t GI_BYTES = (size_t)kT * kN * kG3 * 2;  // 402.7 MB bf16
  if (ws_size >= GI_BYTES) {
    __bf16* gis = (__bf16*)d_ws;
    hipLaunchKernelGGL(gi_gemm, dim3(6, 2048), dim3(256), 0, stream, x, Wih, bih, bhh, gis);
    hipLaunchKernelGGL(gru_scan, dim3(32), dim3(512), 0, stream, gis, h0, done, Whh, bhh, out);
  } else {
    hipLaunchKernelGGL(gru_naive, dim3(32), dim3(256), 0, stream, x, h0, done, Wih, Whh, bih, bhh, out);
  }
}

// Round 2
// 2366.173 us; speedup vs baseline: 1.0124x; 1.0124x over previous
//
#include <hip/hip_runtime.h>

// Problem constants (from reference): T=512, N=512, I=256, H=256
#define kT 512
#define kN 512
#define kH 256
#define kG3 768   // 3*H

typedef float  f32x4  __attribute__((ext_vector_type(4)));
typedef __bf16 bf16x8 __attribute__((ext_vector_type(8)));
typedef __bf16 bf16x4 __attribute__((ext_vector_type(4)));

static __device__ __forceinline__ float sigm(float x) {
  float e = __builtin_amdgcn_exp2f(-1.4426950408889634f * x);
  return __builtin_amdgcn_rcpf(1.0f + e);
}
static __device__ __forceinline__ float tanh_fast(float x) {
  float e = __builtin_amdgcn_exp2f(-2.8853900817779268f * x);
  return fmaf(2.0f, __builtin_amdgcn_rcpf(1.0f + e), -1.0f);
}

// ---------------------------------------------------------------------------
// Phase 1: gi = x @ W_ih^T + b_ih (+ b_hh for r,z), bf16, swizzled layout.
// x-stationary: 2048 blocks, each owns 128 rows of x (staged ONCE in LDS),
// loops over 6 N-tiles of 128 cols, staging W_ih from L2 each tile.
// Block: 512 thr = 8 waves, 2(M) x 4(N).
// ---------------------------------------------------------------------------
__global__ __launch_bounds__(512) void gi_gemm(
    const float* __restrict__ x, const float* __restrict__ Wih,
    const float* __restrict__ bih, const float* __restrict__ bhh,
    __bf16* __restrict__ gis)
{
  __shared__ __align__(16) __bf16 Al[128][264];  // 256 k + 8 pad
  __shared__ __align__(16) __bf16 Bl[128][264];
  const int tid  = threadIdx.x;
  const int lane = tid & 63, w = tid >> 6;
  const int wm = w & 1, wn = w >> 1;            // 2 x 4 wave grid
  const int c = lane & 15, lg = lane >> 4;
  const long R0 = (long)blockIdx.x * 128;
  const int t  = (int)(R0 >> 9);
  const int n0 = (int)(R0 & 511);

  // Stage A tile once (128 rows x 256 k), f32 -> bf16
  #pragma unroll
  for (int it = 0; it < 16; ++it) {
    int slot = tid + it * 512;                  // 0..8191
    int r  = slot >> 6;                         // 0..127
    int kq = (slot & 63) * 4;                   // 0..252
    float4 av = *(const float4*)(x + (R0 + r) * 256 + kq);
    bf16x4 a4 = {(__bf16)av.x, (__bf16)av.y, (__bf16)av.z, (__bf16)av.w};
    *(bf16x4*)(&Al[r][kq]) = a4;
  }

  for (int nb = 0; nb < 6; ++nb) {
    __syncthreads();                            // protect Bl reuse (and Al 1st)
    #pragma unroll
    for (int it = 0; it < 16; ++it) {
      int slot = tid + it * 512;
      int r  = slot >> 6;
      int kq = (slot & 63) * 4;
      float4 bv = *(const float4*)(Wih + (long)(nb * 128 + r) * 256 + kq);
      bf16x4 b4 = {(__bf16)bv.x, (__bf16)bv.y, (__bf16)bv.z, (__bf16)bv.w};
      *(bf16x4*)(&Bl[r][kq]) = b4;
    }
    __syncthreads();

    const int gate = nb >> 1;
    f32x4 acc[4][2];
    #pragma unroll
    for (int nt = 0; nt < 2; ++nt) {
      int j = nb * 128 + wn * 32 + nt * 16 + c;
      float bv = bih[j] + (gate < 2 ? bhh[j] : 0.0f);
      #pragma unroll
      for (int mt = 0; mt < 4; ++mt) acc[mt][nt] = (f32x4){bv, bv, bv, bv};
    }

    #pragma unroll
    for (int ss = 0; ss < 8; ++ss) {
      bf16x8 af[4], bfr[2];
      #pragma unroll
      for (int mt = 0; mt < 4; ++mt)
        af[mt] = *(const bf16x8*)(&Al[wm * 64 + mt * 16 + c][ss * 32 + lg * 8]);
      #pragma unroll
      for (int nt = 0; nt < 2; ++nt)
        bfr[nt] = *(const bf16x8*)(&Bl[wn * 32 + nt * 16 + c][ss * 32 + lg * 8]);
      #pragma unroll
      for (int mt = 0; mt < 4; ++mt)
        #pragma unroll
        for (int nt = 0; nt < 2; ++nt)
          acc[mt][nt] = __builtin_amdgcn_mfma_f32_16x16x32_bf16(af[mt], bfr[nt], acc[mt][nt], 0, 0, 0);
    }

    // Epilogue: one bf16x8 store per mt, matching phase-2 swizzled layout
    const int w2 = (nb & 1) * 4 + wn;
    #pragma unroll
    for (int mt = 0; mt < 4; ++mt) {
      int sb = (n0 >> 4) + wm * 4 + mt;         // 0..31
      bf16x8 v;
      #pragma unroll
      for (int i = 0; i < 4; ++i) {
        v[i]     = (__bf16)acc[mt][0][i];
        v[4 + i] = (__bf16)acc[mt][1][i];
      }
      long base = (((long)(t * 32 + sb) * 8 + w2) * 3 + gate) * 512 + lane * 8;
      *(bf16x8*)(gis + base) = v;
    }
  }
}

// ---------------------------------------------------------------------------
// Phase 2: recurrent scan. 32 blocks x 512 thr (8 waves, 2/SIMD @ 256 VGPR).
// Block b owns seqs [16b,16b+16). W_hh entirely in VGPRs (48 bf16x8 = 192).
// h broadcast via 16KB XOR-swizzled double-buffered LDS. One barrier/step.
// ---------------------------------------------------------------------------
__global__ __launch_bounds__(512, 1) void gru_scan(
    const __bf16* __restrict__ gis, const float* __restrict__ h0,
    const float* __restrict__ done, const float* __restrict__ Whh,
    const float* __restrict__ bhh, float* __restrict__ out)
{
  __shared__ __align__(16) __bf16 hbuf[2][16 * 256];
  const int tid  = threadIdx.x;
  const int lane = tid & 63, w2 = tid >> 6;
  const int b  = blockIdx.x;
  const int nb = b * 16;
  const int c  = lane & 15, lg = lane >> 4;

  // --- W_hh fragments -> registers (bf16). tt = gate*2 + tprime.
  bf16x8 wf[48];
  #pragma unroll
  for (int tt = 0; tt < 6; ++tt) {
    const int g = tt >> 1, tp = tt & 1;
    const int j = g * 256 + w2 * 32 + tp * 16 + c;
    #pragma unroll
    for (int ss = 0; ss < 8; ++ss) {
      const int k0 = ss * 32 + lg * 8;
      float4 q0 = *(const float4*)(Whh + (long)j * 256 + k0);
      float4 q1 = *(const float4*)(Whh + (long)j * 256 + k0 + 4);
      bf16x8 v = {(__bf16)q0.x, (__bf16)q0.y, (__bf16)q0.z, (__bf16)q0.w,
                  (__bf16)q1.x, (__bf16)q1.y, (__bf16)q1.z, (__bf16)q1.w};
      wf[tt * 8 + ss] = v;
    }
  }
  const float bn0 = bhh[512 + w2 * 32 + c];
  const float bn1 = bhh[512 + w2 * 32 + 16 + c];

  // --- init h (scaled by 1-done[0]) into LDS buf0 + per-lane h_old
  {
    const int s  = tid >> 5;
    const int kk = (tid & 31) * 8;
    float sc = 1.0f - done[nb + s];
    const float* hp = h0 + (long)(nb + s) * 256 + kk;
    bf16x8 v;
    #pragma unroll
    for (int e = 0; e < 8; ++e) v[e] = (__bf16)(hp[e] * sc);
    int colb = (kk * 2) ^ ((s & 7) << 4);
    *(bf16x8*)(&hbuf[0][s * 256 + (colb >> 1)]) = v;
  }
  float hold[4][2];
  #pragma unroll
  for (int i = 0; i < 4; ++i) {
    int s = lg * 4 + i;
    float sc = 1.0f - done[nb + s];
    #pragma unroll
    for (int tp = 0; tp < 2; ++tp)
      hold[i][tp] = h0[(long)(nb + s) * 256 + w2 * 32 + tp * 16 + c] * sc;
  }
  __syncthreads();

  // --- prefetch gi(t=0)
  bf16x8 gfr[3];
  {
    long gb = ((long)b * 8 + w2) * 3 * 512 + lane * 8;
    #pragma unroll
    for (int g = 0; g < 3; ++g) gfr[g] = *(const bf16x8*)(gis + gb + g * 512);
  }

  int p = 0;
  #pragma unroll 1
  for (int t = 0; t < kT; ++t) {
    // acc init: r,z tiles from gi (biases folded in phase1); n tiles = b_hh_n
    f32x4 acc[6];
    #pragma unroll
    for (int g = 0; g < 2; ++g)
      #pragma unroll
      for (int tp = 0; tp < 2; ++tp) {
        f32x4 a;
        #pragma unroll
        for (int i = 0; i < 4; ++i) a[i] = (float)gfr[g][tp * 4 + i];
        acc[g * 2 + tp] = a;
      }
    acc[4] = (f32x4){bn0, bn0, bn0, bn0};
    acc[5] = (f32x4){bn1, bn1, bn1, bn1};
    // n-gate gi for THIS step must survive the prefetch below
    float gin[8];
    #pragma unroll
    for (int e = 0; e < 8; ++e) gin[e] = (float)gfr[2][e];

    // prefetch gi(t+1) NOW (gfr regs dead) -> latency hides under MFMA+gates
    {
      int tn = (t < kT - 1) ? t + 1 : t;
      long gb = (((long)tn * 32 + b) * 8 + w2) * 3 * 512 + lane * 8;
      #pragma unroll
      for (int g = 0; g < 3; ++g) gfr[g] = *(const bf16x8*)(gis + gb + g * 512);
    }
    // prefetch done(t+1) (clamped index keeps the load in-bounds, branch-free)
    float dn[4];
    {
      int td = (t < kT - 1) ? t + 1 : t;
      #pragma unroll
      for (int i = 0; i < 4; ++i) {
        float dv = done[(long)td * kN + nb + lg * 4 + i];
        dn[i] = (t < kT - 1) ? dv : 0.0f;
      }
    }

    // MFMA over K=256 (8 slices); A from swizzled LDS, B from registers
    const __bf16* hb = hbuf[p];
    const int rx = (c & 7) << 4;
    #pragma unroll
    for (int ss = 0; ss < 8; ++ss) {
      int colb = (ss * 64 + lg * 16) ^ rx;
      bf16x8 afr = *(const bf16x8*)(&hb[c * 256 + (colb >> 1)]);
      #pragma unroll
      for (int tt = 0; tt < 6; ++tt)
        acc[tt] = __builtin_amdgcn_mfma_f32_16x16x32_bf16(afr, wf[tt * 8 + ss], acc[tt], 0, 0, 0);
    }

    // gates + state update + stores
    float* op = out + ((long)t * kN + nb) * kH;
    __bf16* hw = hbuf[p ^ 1];
    #pragma unroll
    for (int i = 0; i < 4; ++i) {
      const int s = lg * 4 + i;
      #pragma unroll
      for (int tp = 0; tp < 2; ++tp) {
        float r  = sigm(acc[tp][i]);
        float z  = sigm(acc[2 + tp][i]);
        float np = gin[tp * 4 + i] + r * acc[4 + tp][i];
        float n  = tanh_fast(np);
        float ho = hold[i][tp];
        float hn = n + z * (ho - n);
        const int jh = w2 * 32 + tp * 16 + c;
        op[(long)s * kH + jh] = hn;
        float hk = hn * (1.0f - dn[i]);
        hold[i][tp] = hk;
        int colb = (jh * 2) ^ ((s & 7) << 4);
        hw[s * 256 + (colb >> 1)] = (__bf16)hk;
      }
    }

    __syncthreads();
    p ^= 1;
  }

  // final hidden state: hold == h_T (dn forced 0 at t = kT-1)
  float* outF = out + (long)kT * kN * kH;
  #pragma unroll
  for (int i = 0; i < 4; ++i)
    #pragma unroll
    for (int tp = 0; tp < 2; ++tp)
      outF[(long)(nb + lg * 4 + i) * kH + w2 * 32 + tp * 16 + c] = hold[i][tp];
}

// ---------------------------------------------------------------------------
// Fallback (only if ws too small for gi): naive fp32, correct but slow.
// ---------------------------------------------------------------------------
__global__ __launch_bounds__(256) void gru_naive(
    const float* __restrict__ x, const float* __restrict__ h0,
    const float* __restrict__ done, const float* __restrict__ Wih,
    const float* __restrict__ Whh, const float* __restrict__ bih,
    const float* __restrict__ bhh, float* __restrict__ out)
{
  __shared__ float hsA[16][257];
  __shared__ float hsB[16][257];
  const int tid = threadIdx.x;       // column jh
  const int b = blockIdx.x, nb = b * 16;
  for (int s = 0; s < 16; ++s)
    hsA[s][tid] = h0[(long)(nb + s) * 256 + tid] * (1.0f - done[nb + s]);
  __syncthreads();
  float (*hr)[257] = hsA;
  float (*hw)[257] = hsB;
  float* outF = out + (long)kT * kN * kH;
  for (int t = 0; t < kT; ++t) {
    for (int s = 0; s < 16; ++s) {
      const float* xr = x + ((long)t * kN + nb + s) * 256;
      float pr  = bih[tid] + bhh[tid];
      float pz  = bih[256 + tid] + bhh[256 + tid];
      float pnx = bih[512 + tid];
      float pnh = bhh[512 + tid];
      const float* wr = Wih + (long)tid * 256;
      const float* wz = Wih + (long)(256 + tid) * 256;
      const float* wn = Wih + (long)(512 + tid) * 256;
      const float* vr = Whh + (long)tid * 256;
      const float* vz = Whh + (long)(256 + tid) * 256;
      const float* vn = Whh + (long)(512 + tid) * 256;
      #pragma unroll 4
      for (int k = 0; k < 256; ++k) {
        float xv = xr[k], hv = hr[s][k];
        pr  = fmaf(xv, wr[k], pr);  pr  = fmaf(hv, vr[k], pr);
        pz  = fmaf(xv, wz[k], pz);  pz  = fmaf(hv, vz[k], pz);
        pnx = fmaf(xv, wn[k], pnx); pnh = fmaf(hv, vn[k], pnh);
      }
      float r = sigm(pr), z = sigm(pz);
      float n = tanh_fast(pnx + r * pnh);
      float ho = hr[s][tid];
      float hn = n + z * (ho - n);
      out[((long)t * kN + nb + s) * 256 + tid] = hn;
      if (t == kT - 1) outF[(long)(nb + s) * 256 + tid] = hn;
      float d = (t < kT - 1) ? done[(long)(t + 1) * kN + nb + s] : 0.0f;
      hw[s][tid] = hn * (1.0f - d);
    }
    __syncthreads();
    float (*tmp)[257] = hr; hr = hw; hw = tmp;
  }
}

extern "C" void kernel_launch(void* const* d_in, const int* in_sizes, int n_in,
                              void* d_out, int out_size, void* d_ws, size_t ws_size,
                              hipStream_t stream) {
  const float* x    = (const float*)d_in[0];
  const float* h0   = (const float*)d_in[1];
  const float* done = (const float*)d_in[2];
  const float* Wih  = (const float*)d_in[3];
  const float* Whh  = (const float*)d_in[4];
  const float* bih  = (const float*)d_in[5];
  const float* bhh  = (const float*)d_in[6];
  float* out = (float*)d_out;

  const size_t GI_BYTES = (size_t)kT * kN * kG3 * 2;  // 402.7 MB bf16
  if (ws_size >= GI_BYTES) {
    __bf16* gis = (__bf16*)d_ws;
    hipLaunchKernelGGL(gi_gemm, dim3(2048), dim3(512), 0, stream, x, Wih, bih, bhh, gis);
    hipLaunchKernelGGL(gru_scan, dim3(32), dim3(512), 0, stream, gis, h0, done, Whh, bhh, out);
  } else {
    hipLaunchKernelGGL(gru_naive, dim3(32), dim3(256), 0, stream, x, h0, done, Wih, Whh, bih, bhh, out);
  }
}

// Round 3
// 2009.539 us; speedup vs baseline: 1.1921x; 1.1775x over previous
//
#include <hip/hip_runtime.h>

// Problem constants (from reference): T=512, N=512, I=256, H=256
#define kT 512
#define kN 512
#define kH 256

typedef float  f32x4  __attribute__((ext_vector_type(4)));
typedef __bf16 bf16x8 __attribute__((ext_vector_type(8)));
typedef __bf16 bf16x4 __attribute__((ext_vector_type(4)));

static __device__ __forceinline__ float sigm(float x) {
  float e = __builtin_amdgcn_exp2f(-1.4426950408889634f * x);
  return __builtin_amdgcn_rcpf(1.0f + e);
}
static __device__ __forceinline__ float tanh_fast(float x) {
  float e = __builtin_amdgcn_exp2f(-2.8853900817779268f * x);
  return fmaf(2.0f, __builtin_amdgcn_rcpf(1.0f + e), -1.0f);
}

// ---------------------------------------------------------------------------
// Phase 1: gi = x @ W_ih^T + b_ih (+ b_hh for r,z), bf16, swizzled layout.
// x-stationary: 2048 blocks x 512 thr; A staged once, 6 W-tiles from L2.
// Layout out: gi[t][sb(32)][w2(8)][gate(3)][lane(64)][8 bf16]
// ---------------------------------------------------------------------------
__global__ __launch_bounds__(512) void gi_gemm(
    const float* __restrict__ x, const float* __restrict__ Wih,
    const float* __restrict__ bih, const float* __restrict__ bhh,
    __bf16* __restrict__ gis)
{
  __shared__ __align__(16) __bf16 Al[128][264];  // 256 k + 8 pad
  __shared__ __align__(16) __bf16 Bl[128][264];
  const int tid  = threadIdx.x;
  const int lane = tid & 63, w = tid >> 6;
  const int wm = w & 1, wn = w >> 1;            // 2 x 4 wave grid
  const int c = lane & 15, lg = lane >> 4;
  const long R0 = (long)blockIdx.x * 128;
  const int t  = (int)(R0 >> 9);
  const int n0 = (int)(R0 & 511);

  #pragma unroll
  for (int it = 0; it < 16; ++it) {
    int slot = tid + it * 512;
    int r  = slot >> 6;
    int kq = (slot & 63) * 4;
    float4 av = *(const float4*)(x + (R0 + r) * 256 + kq);
    bf16x4 a4 = {(__bf16)av.x, (__bf16)av.y, (__bf16)av.z, (__bf16)av.w};
    *(bf16x4*)(&Al[r][kq]) = a4;
  }

  for (int nb = 0; nb < 6; ++nb) {
    __syncthreads();
    #pragma unroll
    for (int it = 0; it < 16; ++it) {
      int slot = tid + it * 512;
      int r  = slot >> 6;
      int kq = (slot & 63) * 4;
      float4 bv = *(const float4*)(Wih + (long)(nb * 128 + r) * 256 + kq);
      bf16x4 b4 = {(__bf16)bv.x, (__bf16)bv.y, (__bf16)bv.z, (__bf16)bv.w};
      *(bf16x4*)(&Bl[r][kq]) = b4;
    }
    __syncthreads();

    const int gate = nb >> 1;
    f32x4 acc[4][2];
    #pragma unroll
    for (int nt = 0; nt < 2; ++nt) {
      int j = nb * 128 + wn * 32 + nt * 16 + c;
      float bv = bih[j] + (gate < 2 ? bhh[j] : 0.0f);
      #pragma unroll
      for (int mt = 0; mt < 4; ++mt) acc[mt][nt] = (f32x4){bv, bv, bv, bv};
    }

    #pragma unroll
    for (int ss = 0; ss < 8; ++ss) {
      bf16x8 af[4], bfr[2];
      #pragma unroll
      for (int mt = 0; mt < 4; ++mt)
        af[mt] = *(const bf16x8*)(&Al[wm * 64 + mt * 16 + c][ss * 32 + lg * 8]);
      #pragma unroll
      for (int nt = 0; nt < 2; ++nt)
        bfr[nt] = *(const bf16x8*)(&Bl[wn * 32 + nt * 16 + c][ss * 32 + lg * 8]);
      #pragma unroll
      for (int mt = 0; mt < 4; ++mt)
        #pragma unroll
        for (int nt = 0; nt < 2; ++nt)
          acc[mt][nt] = __builtin_amdgcn_mfma_f32_16x16x32_bf16(af[mt], bfr[nt], acc[mt][nt], 0, 0, 0);
    }

    const int w2 = (nb & 1) * 4 + wn;
    #pragma unroll
    for (int mt = 0; mt < 4; ++mt) {
      int sb = (n0 >> 4) + wm * 4 + mt;
      bf16x8 v;
      #pragma unroll
      for (int i = 0; i < 4; ++i) {
        v[i]     = (__bf16)acc[mt][0][i];
        v[4 + i] = (__bf16)acc[mt][1][i];
      }
      long base = (((long)(t * 32 + sb) * 8 + w2) * 3 + gate) * 512 + lane * 8;
      *(bf16x8*)(gis + base) = v;
    }
  }
}

// ---------------------------------------------------------------------------
// Phase 2: recurrent scan. 32 blocks x 512 thr (8 waves @ <=256 VGPR, pinned
// via amdgpu_waves_per_eu(2,2)). W_hh in 192 pinned VGPRs. gi via 4-deep
// global_load_lds pipeline (counted vmcnt, raw s_barrier -- no vmem drain).
// done pre-staged packed-u8 in LDS. One barrier/step.
// ---------------------------------------------------------------------------
__global__ __attribute__((amdgpu_waves_per_eu(2, 2))) __launch_bounds__(512)
void gru_scan(
    const __bf16* __restrict__ gis, const float* __restrict__ h0,
    const float* __restrict__ done, const float* __restrict__ Whh,
    const float* __restrict__ bhh, float* __restrict__ out)
{
  __shared__ __align__(16) __bf16 hbuf[2][16 * 256];   // 16 KB
  __shared__ __align__(16) __bf16 gibuf[4][12288];     // 96 KB (4 x 24 KB)
  __shared__ unsigned char doneL[kT * 16];             // 8 KB (shifted: row t = done[t+1])

  const int tid  = threadIdx.x;
  const int lane = tid & 63, w2 = tid >> 6;
  const int b  = blockIdx.x;
  const int nb = b * 16;
  const int c  = lane & 15, lg = lane >> 4;

  // --- W_hh fragments -> VGPRs, pinned against rematerialization.
  f32x4 wf[48];
  #pragma unroll
  for (int tt = 0; tt < 6; ++tt) {
    const int g = tt >> 1, tp = tt & 1;
    const int j = g * 256 + w2 * 32 + tp * 16 + c;
    #pragma unroll
    for (int ss = 0; ss < 8; ++ss) {
      const int k0 = ss * 32 + lg * 8;
      float4 q0 = *(const float4*)(Whh + (long)j * 256 + k0);
      float4 q1 = *(const float4*)(Whh + (long)j * 256 + k0 + 4);
      bf16x8 v = {(__bf16)q0.x, (__bf16)q0.y, (__bf16)q0.z, (__bf16)q0.w,
                  (__bf16)q1.x, (__bf16)q1.y, (__bf16)q1.z, (__bf16)q1.w};
      wf[tt * 8 + ss] = __builtin_bit_cast(f32x4, v);
    }
  }
  #pragma unroll
  for (int i = 0; i < 48; ++i) asm volatile("" : "+v"(wf[i]));

  const float bn0 = bhh[512 + w2 * 32 + c];
  const float bn1 = bhh[512 + w2 * 32 + 16 + c];

  // --- done -> LDS, shifted by 1 (row t holds done[t+1]; last row = 0)
  for (int idx = tid; idx < (kT - 1) * 16; idx += 512) {
    int tt = idx >> 4, s = idx & 15;
    doneL[idx] = (unsigned char)(done[(long)(tt + 1) * kN + nb + s] != 0.0f);
  }
  if (tid < 16) doneL[(kT - 1) * 16 + tid] = 0;

  // --- init h (scaled by 1-done[0]) into LDS buf0 + per-lane h_old
  {
    const int s  = tid >> 5;
    const int kk = (tid & 31) * 8;
    float sc = 1.0f - done[nb + s];
    const float* hp = h0 + (long)(nb + s) * 256 + kk;
    bf16x8 v;
    #pragma unroll
    for (int e = 0; e < 8; ++e) v[e] = (__bf16)(hp[e] * sc);
    int colb = (kk * 2) ^ ((s & 7) << 4);
    *(bf16x8*)(&hbuf[0][s * 256 + (colb >> 1)]) = v;
  }
  float hold[4][2];
  #pragma unroll
  for (int i = 0; i < 4; ++i) {
    int s = lg * 4 + i;
    float sc = 1.0f - done[nb + s];
    #pragma unroll
    for (int tp = 0; tp < 2; ++tp)
      hold[i][tp] = h0[(long)(nb + s) * 256 + w2 * 32 + tp * 16 + c] * sc;
  }

  // --- prologue: issue gi loads for t=0,1,2 into LDS, drain, barrier
  #pragma unroll
  for (int tt = 0; tt < 3; ++tt) {
    const __bf16* src = gis + (((long)tt * 32 + b) * 8 + w2) * 1536 + lane * 8;
    #pragma unroll
    for (int g = 0; g < 3; ++g)
      __builtin_amdgcn_global_load_lds(
          (const __attribute__((address_space(1))) unsigned int*)(src + g * 512),
          (__attribute__((address_space(3))) unsigned int*)(&gibuf[tt][w2 * 1536 + g * 512]),
          16, 0, 0);
  }
  asm volatile("s_waitcnt vmcnt(0)" ::: "memory");
  __syncthreads();

  #pragma unroll 1
  for (int t = 0; t < kT; ++t) {
    // steady state: 22 vmem ops issued after this step's gi loads
    // (S(t-2)x8, L(t+1)x3, S(t-1)x8, L(t+2)x3) -> vmcnt(22) guarantees L(t).
    asm volatile("s_waitcnt vmcnt(22)" ::: "memory");
    __builtin_amdgcn_sched_barrier(0);

    const __bf16* gib = &gibuf[t & 3][w2 * 1536 + lane * 8];
    bf16x8 g0 = *(const bf16x8*)(gib);          // r-gate gi (bias folded)
    bf16x8 g1 = *(const bf16x8*)(gib + 512);    // z-gate gi (bias folded)
    bf16x8 g2 = *(const bf16x8*)(gib + 1024);   // n-gate gi (b_ih only)
    unsigned du = *(const unsigned*)(&doneL[t * 16 + lg * 4]);

    f32x4 acc[6];
    #pragma unroll
    for (int i = 0; i < 4; ++i) {
      acc[0][i] = (float)g0[i];
      acc[1][i] = (float)g0[4 + i];
      acc[2][i] = (float)g1[i];
      acc[3][i] = (float)g1[4 + i];
    }
    acc[4] = (f32x4){bn0, bn0, bn0, bn0};
    acc[5] = (f32x4){bn1, bn1, bn1, bn1};

    // MFMA over K=256 (8 slices); A from swizzled LDS, B from pinned regs
    const __bf16* hb = hbuf[t & 1];
    const int rx = (c & 7) << 4;
    #pragma unroll
    for (int ss = 0; ss < 8; ++ss) {
      int colb = (ss * 64 + lg * 16) ^ rx;
      bf16x8 afr = *(const bf16x8*)(&hb[c * 256 + (colb >> 1)]);
      #pragma unroll
      for (int tt = 0; tt < 6; ++tt)
        acc[tt] = __builtin_amdgcn_mfma_f32_16x16x32_bf16(
            afr, __builtin_bit_cast(bf16x8, wf[tt * 8 + ss]), acc[tt], 0, 0, 0);
    }

    // gates + state update + stores
    float* op = out + ((long)t * kN + nb) * kH;
    __bf16* hw = hbuf[(t & 1) ^ 1];
    #pragma unroll
    for (int i = 0; i < 4; ++i) {
      const int s = lg * 4 + i;
      const float dn = (float)((du >> (8 * i)) & 255u);
      #pragma unroll
      for (int tp = 0; tp < 2; ++tp) {
        float r  = sigm(acc[tp][i]);
        float z  = sigm(acc[2 + tp][i]);
        float npv = (float)g2[tp * 4 + i] + r * acc[4 + tp][i];
        float n  = tanh_fast(npv);
        float ho = hold[i][tp];
        float hn = n + z * (ho - n);
        const int jh = w2 * 32 + tp * 16 + c;
        op[(long)s * kH + jh] = hn;
        float hk = hn * (1.0f - dn);
        hold[i][tp] = hk;
        int colb2 = (jh * 2) ^ ((s & 7) << 4);
        hw[s * 256 + (colb2 >> 1)] = (__bf16)hk;
      }
    }

    // issue gi loads for t+3 (uniform guard; skipped iters only loosen vmcnt)
    if (t < kT - 3) {
      const __bf16* src = gis + (((long)(t + 3) * 32 + b) * 8 + w2) * 1536 + lane * 8;
      __bf16* dst = &gibuf[(t + 3) & 3][w2 * 1536];
      #pragma unroll
      for (int g = 0; g < 3; ++g)
        __builtin_amdgcn_global_load_lds(
            (const __attribute__((address_space(1))) unsigned int*)(src + g * 512),
            (__attribute__((address_space(3))) unsigned int*)(dst + g * 512),
            16, 0, 0);
    }

    // h visible to all waves; gi loads stay in flight across the barrier
    asm volatile("s_waitcnt lgkmcnt(0)" ::: "memory");
    __builtin_amdgcn_s_barrier();
  }

  // final hidden state (dn forced 0 at t=kT-1 via doneL last row)
  float* outF = out + (long)kT * kN * kH;
  #pragma unroll
  for (int i = 0; i < 4; ++i)
    #pragma unroll
    for (int tp = 0; tp < 2; ++tp)
      outF[(long)(nb + lg * 4 + i) * kH + w2 * 32 + tp * 16 + c] = hold[i][tp];
}

// ---------------------------------------------------------------------------
// Fallback (only if ws too small for gi): naive fp32, correct but slow.
// ---------------------------------------------------------------------------
__global__ __launch_bounds__(256) void gru_naive(
    const float* __restrict__ x, const float* __restrict__ h0,
    const float* __restrict__ done, const float* __restrict__ Wih,
    const float* __restrict__ Whh, const float* __restrict__ bih,
    const float* __restrict__ bhh, float* __restrict__ out)
{
  __shared__ float hsA[16][257];
  __shared__ float hsB[16][257];
  const int tid = threadIdx.x;
  const int b = blockIdx.x, nb = b * 16;
  for (int s = 0; s < 16; ++s)
    hsA[s][tid] = h0[(long)(nb + s) * 256 + tid] * (1.0f - done[nb + s]);
  __syncthreads();
  float (*hr)[257] = hsA;
  float (*hw)[257] = hsB;
  float* outF = out + (long)kT * kN * kH;
  for (int t = 0; t < kT; ++t) {
    for (int s = 0; s < 16; ++s) {
      const float* xr = x + ((long)t * kN + nb + s) * 256;
      float pr  = bih[tid] + bhh[tid];
      float pz  = bih[256 + tid] + bhh[256 + tid];
      float pnx = bih[512 + tid];
      float pnh = bhh[512 + tid];
      const float* wr = Wih + (long)tid * 256;
      const float* wz = Wih + (long)(256 + tid) * 256;
      const float* wn = Wih + (long)(512 + tid) * 256;
      const float* vr = Whh + (long)tid * 256;
      const float* vz = Whh + (long)(256 + tid) * 256;
      const float* vn = Whh + (long)(512 + tid) * 256;
      #pragma unroll 4
      for (int k = 0; k < 256; ++k) {
        float xv = xr[k], hv = hr[s][k];
        pr  = fmaf(xv, wr[k], pr);  pr  = fmaf(hv, vr[k], pr);
        pz  = fmaf(xv, wz[k], pz);  pz  = fmaf(hv, vz[k], pz);
        pnx = fmaf(xv, wn[k], pnx); pnh = fmaf(hv, vn[k], pnh);
      }
      float r = sigm(pr), z = sigm(pz);
      float n = tanh_fast(pnx + r * pnh);
      float ho = hr[s][tid];
      float hn = n + z * (ho - n);
      out[((long)t * kN + nb + s) * 256 + tid] = hn;
      if (t == kT - 1) outF[(long)(nb + s) * 256 + tid] = hn;
      float d = (t < kT - 1) ? done[(long)(t + 1) * kN + nb + s] : 0.0f;
      hw[s][tid] = hn * (1.0f - d);
    }
    __syncthreads();
    float (*tmp)[257] = hr; hr = hw; hw = tmp;
  }
}

extern "C" void kernel_launch(void* const* d_in, const int* in_sizes, int n_in,
                              void* d_out, int out_size, void* d_ws, size_t ws_size,
                              hipStream_t stream) {
  const float* x    = (const float*)d_in[0];
  const float* h0   = (const float*)d_in[1];
  const float* done = (const float*)d_in[2];
  const float* Whh  = (const float*)d_in[4];
  const float* Wih  = (const float*)d_in[3];
  const float* bih  = (const float*)d_in[5];
  const float* bhh  = (const float*)d_in[6];
  float* out = (float*)d_out;

  const size_t GI_BYTES = (size_t)kT * kN * 768 * 2;  // 402.7 MB bf16
  if (ws_size >= GI_BYTES) {
    __bf16* gis = (__bf16*)d_ws;
    hipLaunchKernelGGL(gi_gemm, dim3(2048), dim3(512), 0, stream, x, Wih, bih, bhh, gis);
    hipLaunchKernelGGL(gru_scan, dim3(32), dim3(512), 0, stream, gis, h0, done, Whh, bhh, out);
  } else {
    hipLaunchKernelGGL(gru_naive, dim3(32), dim3(256), 0, stream, x, h0, done, Wih, Whh, bih, bhh, out);
  }
}